// Round 1
// 793.671 us; speedup vs baseline: 1.2789x; 1.2789x over previous
//
#include <hip/hip_runtime.h>

// Wide & Deep forward, MI355X.
// K1: gather embeddings + 2-layer MLP -> h2 (4096x128) bf16 into d_ws.
// Kg: materialize wide term Wg[j][b] = bf16(w_head[j, items[b]]), row-major rows
//     so each 40KB w_head row is fetched from HBM exactly once (L1/L2-hot reuse).
// K2: fused head: out = sigmoid(h2 @ Wd^T + Wg + b_head), 128x128 MFMA tiles,
//     wide term read coalesced from Wg instead of 41M scattered 4B gathers.

#define BATCH    4096
#define NITEMS   10000
#define HEADCOLS 10128   // 10000 one-hot + 128 dense
#define DENSEOFF 10000

typedef __attribute__((ext_vector_type(8))) short short8;
typedef __attribute__((ext_vector_type(4))) short short4v;
typedef __attribute__((ext_vector_type(4))) float floatx4;

__device__ inline unsigned short f2bf(float f) {
    unsigned u = __builtin_bit_cast(unsigned, f);
    unsigned r = (u + 0x7FFFu + ((u >> 16) & 1u)) >> 16;
    return (unsigned short)r;
}

__device__ inline float bf2f(unsigned short u) {
    unsigned x = ((unsigned)u) << 16;
    return __builtin_bit_cast(float, x);
}

// ---------------- K1: embeddings + MLP -> h2 (bf16) ----------------
// 256 blocks x 256 threads; each block handles 16 batch rows.
__global__ __launch_bounds__(256) void k1_mlp(
    const int* __restrict__ inter,
    const float* __restrict__ U, const float* __restrict__ I,
    const float* __restrict__ w1, const float* __restrict__ b1,
    const float* __restrict__ w2, const float* __restrict__ b2,
    unsigned short* __restrict__ h2b)
{
    __shared__ float e_lds[16 * 64];
    __shared__ float h1_lds[16 * 128];
    const int t  = threadIdx.x;
    const int b0 = blockIdx.x * 16;

    // stage concat(user_emb, item_emb): 16 rows x 64
    for (int idx = t; idx < 16 * 64; idx += 256) {
        int b = idx >> 6, d = idx & 63;
        int u  = inter[2 * (b0 + b)];
        int it = inter[2 * (b0 + b) + 1];
        e_lds[idx] = (d < 32) ? U[(long)u * 32 + d] : I[(long)it * 32 + (d - 32)];
    }
    __syncthreads();

    // layer 1: h1[b][i] = relu(w1[i,:] . e[b,:] + b1[i])
    {
        const int i  = t & 127;
        const int bh = (t >> 7) * 8;      // 2 half-groups x 8 rows
        float acc[8];
        #pragma unroll
        for (int b = 0; b < 8; b++) acc[b] = b1[i];
        for (int d = 0; d < 64; d += 4) {
            float4 w = *(const float4*)&w1[i * 64 + d];
            #pragma unroll
            for (int b = 0; b < 8; b++) {
                const float* e = &e_lds[(bh + b) * 64 + d];  // LDS broadcast
                acc[b] += w.x * e[0] + w.y * e[1] + w.z * e[2] + w.w * e[3];
            }
        }
        #pragma unroll
        for (int b = 0; b < 8; b++) h1_lds[(bh + b) * 128 + i] = fmaxf(acc[b], 0.f);
    }
    __syncthreads();

    // layer 2: h2[b][o] = relu(w2[o,:] . h1[b,:] + b2[o]) -> bf16
    {
        const int o  = t & 127;
        const int bh = (t >> 7) * 8;
        float acc[8];
        #pragma unroll
        for (int b = 0; b < 8; b++) acc[b] = b2[o];
        for (int k = 0; k < 128; k += 4) {
            float4 w = *(const float4*)&w2[o * 128 + k];
            #pragma unroll
            for (int b = 0; b < 8; b++) {
                const float* h = &h1_lds[(bh + b) * 128 + k];  // LDS broadcast
                acc[b] += w.x * h[0] + w.y * h[1] + w.z * h[2] + w.w * h[3];
            }
        }
        #pragma unroll
        for (int b = 0; b < 8; b++)
            h2b[(long)(b0 + bh + b) * 128 + o] = f2bf(fmaxf(acc[b], 0.f));
    }
}

// ---------------- Kg: wide-term gather, row-at-a-time ----------------
// 1250 blocks x 256 threads; block owns 8 w_head rows and ALL 4096 batch slots.
// Per row: 4096 gathers land inside one 40KB row -> its ~625 lines are pulled
// from HBM once and reused ~6.5x from L1/L2. Writes Wg[j][b] bf16, coalesced.
#define KG_ROWS 8
__global__ __launch_bounds__(256) void kg_gather(
    const int* __restrict__ inter,
    const float* __restrict__ w_head,
    unsigned short* __restrict__ wg)
{
    const int t  = threadIdx.x;
    const int j0 = blockIdx.x * KG_ROWS;

    // this thread's 16 item indices (b = t + 256*i), kept in registers
    int c[16];
    #pragma unroll
    for (int i = 0; i < 16; i++) c[i] = inter[2 * (t + 256 * i) + 1];

    for (int r = 0; r < KG_ROWS; r++) {
        const float* row = w_head + (long)(j0 + r) * HEADCOLS;
        unsigned short* wr = wg + (long)(j0 + r) * BATCH;
        float w[16];
        #pragma unroll
        for (int i = 0; i < 16; i++) w[i] = row[c[i]];     // 16 loads in flight
        #pragma unroll
        for (int i = 0; i < 16; i++)
            __builtin_nontemporal_store(f2bf(w[i]), &wr[t + 256 * i]);
    }
}

// ---------------- K2: fused head (Wg path) ----------------
// Tile 128(b) x 128(j), 4 waves (2x2), 16x16x32 bf16 MFMA, K=128 in one shot.
#define LDSTR 136   // 128 + 8 bf16 pad (16B-aligned rows, 2-way-max bank aliasing)

__global__ __launch_bounds__(256) void k2_head(
    const unsigned short* __restrict__ h2b,
    const float* __restrict__ w_head, const float* __restrict__ b_head,
    const unsigned short* __restrict__ wg, float* __restrict__ out)
{
    __shared__ short A_lds[128 * LDSTR];
    __shared__ short B_lds[128 * LDSTR];

    const int t     = threadIdx.x;
    const int bbase = blockIdx.x * 128;   // b-tiles fast -> adjacent blocks share j-tile (L2/L3 reuse)
    const int jbase = blockIdx.y * 128;

    // stage A: h2 tile (128 x 128 bf16), 16B chunks
    for (int idx = t; idx < 128 * 16; idx += 256) {
        int r = idx >> 4, s = idx & 15;
        short8 v = *(const short8*)&h2b[(long)(bbase + r) * 128 + s * 8];
        *(short8*)&A_lds[r * LDSTR + s * 8] = v;
    }
    // stage B: dense cols of w_head (128 x 128), f32 -> bf16
    for (int idx = t; idx < 128 * 32; idx += 256) {
        int r = idx >> 5, s = idx & 31;
        int j = jbase + r;
        short4v o4;
        if (j < NITEMS) {
            float4 w = *(const float4*)&w_head[(long)j * HEADCOLS + DENSEOFF + s * 4];
            o4[0] = (short)f2bf(w.x); o4[1] = (short)f2bf(w.y);
            o4[2] = (short)f2bf(w.z); o4[3] = (short)f2bf(w.w);
        } else {
            o4[0] = 0; o4[1] = 0; o4[2] = 0; o4[3] = 0;
        }
        *(short4v*)&B_lds[r * LDSTR + s * 4] = o4;
    }
    __syncthreads();

    const int lane = t & 63, wave = t >> 6;
    const int wb = (wave & 1) * 64, wj = (wave >> 1) * 64;
    const int col = lane & 15, quad = lane >> 4;

    floatx4 acc[4][4];
    #pragma unroll
    for (int bi = 0; bi < 4; bi++)
        #pragma unroll
        for (int ji = 0; ji < 4; ji++)
            #pragma unroll
            for (int r = 0; r < 4; r++) acc[bi][ji][r] = 0.f;

    // K = 128 = 4 x 32
    #pragma unroll
    for (int ks = 0; ks < 4; ks++) {
        short8 a[4], b[4];
        #pragma unroll
        for (int bi = 0; bi < 4; bi++)
            a[bi] = *(const short8*)&A_lds[(wb + bi * 16 + col) * LDSTR + ks * 32 + quad * 8];
        #pragma unroll
        for (int ji = 0; ji < 4; ji++)
            b[ji] = *(const short8*)&B_lds[(wj + ji * 16 + col) * LDSTR + ks * 32 + quad * 8];
        #pragma unroll
        for (int bi = 0; bi < 4; bi++)
            #pragma unroll
            for (int ji = 0; ji < 4; ji++)
                acc[bi][ji] = __builtin_amdgcn_mfma_f32_16x16x32_bf16(a[bi], b[ji], acc[bi][ji], 0, 0, 0);
    }

    // epilogue: + bias + wide (coalesced from Wg), sigmoid, store.
    // C/D layout: col = lane&15, row = quad*4 + reg  (m89-verified)
    #pragma unroll
    for (int ji = 0; ji < 4; ji++) {
        int j = jbase + wj + ji * 16 + col;
        bool jv = (j < NITEMS);
        float bias = jv ? b_head[j] : 0.f;
        const unsigned short* wgr = wg + (long)(jv ? j : 0) * BATCH + bbase;
        #pragma unroll
        for (int bi = 0; bi < 4; bi++) {
            short4v wv = *(const short4v*)&wgr[wb + bi * 16 + quad * 4];   // 8B coalesced
            #pragma unroll
            for (int r = 0; r < 4; r++) {
                int bl = wb + bi * 16 + quad * 4 + r;
                float wide = bf2f((unsigned short)wv[r]);
                float x = acc[bi][ji][r] + bias + wide;
                float y = 1.f / (1.f + __expf(-x));
                if (jv) __builtin_nontemporal_store(y, &out[(long)(bbase + bl) * NITEMS + j]);
            }
        }
    }
}

// ---------------- K2 fallback: original scattered-gather head ----------------
// Used only if workspace can't hold Wg (82 MB).
__global__ __launch_bounds__(256) void k2_head_fb(
    const unsigned short* __restrict__ h2b,
    const float* __restrict__ w_head, const float* __restrict__ b_head,
    const int* __restrict__ inter, float* __restrict__ out)
{
    __shared__ short A_lds[128 * LDSTR];
    __shared__ short B_lds[128 * LDSTR];
    __shared__ int items[128];

    const int t     = threadIdx.x;
    const int bbase = blockIdx.x * 128;
    const int jbase = blockIdx.y * 128;

    if (t < 128) items[t] = inter[2 * (bbase + t) + 1];

    for (int idx = t; idx < 128 * 16; idx += 256) {
        int r = idx >> 4, s = idx & 15;
        short8 v = *(const short8*)&h2b[(long)(bbase + r) * 128 + s * 8];
        *(short8*)&A_lds[r * LDSTR + s * 8] = v;
    }
    for (int idx = t; idx < 128 * 32; idx += 256) {
        int r = idx >> 5, s = idx & 31;
        int j = jbase + r;
        short4v o4;
        if (j < NITEMS) {
            float4 w = *(const float4*)&w_head[(long)j * HEADCOLS + DENSEOFF + s * 4];
            o4[0] = (short)f2bf(w.x); o4[1] = (short)f2bf(w.y);
            o4[2] = (short)f2bf(w.z); o4[3] = (short)f2bf(w.w);
        } else {
            o4[0] = 0; o4[1] = 0; o4[2] = 0; o4[3] = 0;
        }
        *(short4v*)&B_lds[r * LDSTR + s * 4] = o4;
    }
    __syncthreads();

    const int lane = t & 63, wave = t >> 6;
    const int wb = (wave & 1) * 64, wj = (wave >> 1) * 64;
    const int col = lane & 15, quad = lane >> 4;

    floatx4 acc[4][4];
    #pragma unroll
    for (int bi = 0; bi < 4; bi++)
        #pragma unroll
        for (int ji = 0; ji < 4; ji++)
            #pragma unroll
            for (int r = 0; r < 4; r++) acc[bi][ji][r] = 0.f;

    #pragma unroll
    for (int ks = 0; ks < 4; ks++) {
        short8 a[4], b[4];
        #pragma unroll
        for (int bi = 0; bi < 4; bi++)
            a[bi] = *(const short8*)&A_lds[(wb + bi * 16 + col) * LDSTR + ks * 32 + quad * 8];
        #pragma unroll
        for (int ji = 0; ji < 4; ji++)
            b[ji] = *(const short8*)&B_lds[(wj + ji * 16 + col) * LDSTR + ks * 32 + quad * 8];
        #pragma unroll
        for (int bi = 0; bi < 4; bi++)
            #pragma unroll
            for (int ji = 0; ji < 4; ji++)
                acc[bi][ji] = __builtin_amdgcn_mfma_f32_16x16x32_bf16(a[bi], b[ji], acc[bi][ji], 0, 0, 0);
    }

    #pragma unroll
    for (int ji = 0; ji < 4; ji++) {
        int j = jbase + wj + ji * 16 + col;
        bool jv = (j < NITEMS);
        float bias = jv ? b_head[j] : 0.f;
        const float* wrow = w_head + (long)(jv ? j : 0) * HEADCOLS;
        #pragma unroll
        for (int bi = 0; bi < 4; bi++) {
            #pragma unroll
            for (int r = 0; r < 4; r++) {
                int bl = wb + bi * 16 + quad * 4 + r;
                float wide = jv ? wrow[items[bl]] : 0.f;
                float x = acc[bi][ji][r] + bias + wide;
                float y = 1.f / (1.f + __expf(-x));
                if (jv) out[(long)(bbase + bl) * NITEMS + j] = y;
            }
        }
    }
}

extern "C" void kernel_launch(void* const* d_in, const int* in_sizes, int n_in,
                              void* d_out, int out_size, void* d_ws, size_t ws_size,
                              hipStream_t stream) {
    const int*   inter = (const int*)d_in[0];
    const float* U     = (const float*)d_in[1];
    const float* I     = (const float*)d_in[2];
    const float* w1    = (const float*)d_in[3];
    const float* b1    = (const float*)d_in[4];
    const float* w2    = (const float*)d_in[5];
    const float* b2    = (const float*)d_in[6];
    const float* wh    = (const float*)d_in[7];
    const float* bh    = (const float*)d_in[8];
    float* out = (float*)d_out;

    unsigned short* h2b = (unsigned short*)d_ws;   // 4096*128 bf16 = 1 MB
    const size_t WG_OFF  = 1u << 20;
    const size_t WG_SIZE = (size_t)NITEMS * BATCH * 2;  // 82 MB bf16

    k1_mlp<<<256, 256, 0, stream>>>(inter, U, I, w1, b1, w2, b2, h2b);

    if (ws_size >= WG_OFF + WG_SIZE) {
        unsigned short* wg = (unsigned short*)((char*)d_ws + WG_OFF);
        kg_gather<<<NITEMS / KG_ROWS, 256, 0, stream>>>(inter, wh, wg);
        k2_head<<<dim3(32, 79), 256, 0, stream>>>(h2b, wh, bh, wg, out);
    } else {
        k2_head_fb<<<dim3(32, 79), 256, 0, stream>>>(h2b, wh, bh, inter, out);
    }
}

// Round 3
// 691.261 us; speedup vs baseline: 1.4683x; 1.1481x over previous
//
#include <hip/hip_runtime.h>

// Wide & Deep forward, MI355X.
// K1: gather embeddings + 2-layer MLP -> h2 (4096x128) bf16 into d_ws.
// Kg: per w_head row: stage 40.5KB row to LDS (coalesced float4), gather the
//     4096 wide terms from LDS (row > 32KB L1, so L1/L2 gathers were txn-bound),
//     write Wg[j][b] bf16 packed; also emit dense cols as bf16 Wd[j][128].
// K2: fused head: out = sigmoid(h2 @ Wd^T + Wg + b_head), 128x128 MFMA tiles.

#define BATCH    4096
#define NITEMS   10000
#define HEADCOLS 10128   // 10000 one-hot + 128 dense
#define DENSEOFF 10000

typedef __attribute__((ext_vector_type(8))) short short8;
typedef __attribute__((ext_vector_type(4))) short short4v;
typedef __attribute__((ext_vector_type(4))) float floatx4;

__device__ inline unsigned short f2bf(float f) {
    unsigned u = __builtin_bit_cast(unsigned, f);
    unsigned r = (u + 0x7FFFu + ((u >> 16) & 1u)) >> 16;
    return (unsigned short)r;
}

__device__ inline float bf2f(unsigned short u) {
    unsigned x = ((unsigned)u) << 16;
    return __builtin_bit_cast(float, x);
}

// ---------------- K1: embeddings + MLP -> h2 (bf16) ----------------
// 512 blocks x 256 threads; each block handles 8 batch rows.
// float4 LDS reads (broadcast across the 128 i-lanes), 2 groups x 4 rows.
__global__ __launch_bounds__(256) void k1_mlp(
    const int* __restrict__ inter,
    const float* __restrict__ U, const float* __restrict__ I,
    const float* __restrict__ w1, const float* __restrict__ b1,
    const float* __restrict__ w2, const float* __restrict__ b2,
    unsigned short* __restrict__ h2b)
{
    __shared__ float e_lds[8 * 64];
    __shared__ float h1_lds[8 * 128];
    const int t  = threadIdx.x;
    const int b0 = blockIdx.x * 8;

    // stage concat(user_emb, item_emb): 8 rows x 64
    for (int idx = t; idx < 8 * 64; idx += 256) {
        int b = idx >> 6, d = idx & 63;
        int u  = inter[2 * (b0 + b)];
        int it = inter[2 * (b0 + b) + 1];
        e_lds[idx] = (d < 32) ? U[(long)u * 32 + d] : I[(long)it * 32 + (d - 32)];
    }
    __syncthreads();

    const int i = t & 127;
    const int g = (t >> 7) * 4;   // 2 groups x 4 rows

    // layer 1: h1[b][i] = relu(w1[i,:] . e[b,:] + b1[i])
    {
        float acc[4];
        #pragma unroll
        for (int b = 0; b < 4; b++) acc[b] = b1[i];
        for (int d = 0; d < 64; d += 4) {
            float4 w = *(const float4*)&w1[i * 64 + d];
            #pragma unroll
            for (int b = 0; b < 4; b++) {
                float4 e = *(const float4*)&e_lds[(g + b) * 64 + d];  // ds_read_b128, broadcast
                acc[b] += w.x * e.x + w.y * e.y + w.z * e.z + w.w * e.w;
            }
        }
        #pragma unroll
        for (int b = 0; b < 4; b++) h1_lds[(g + b) * 128 + i] = fmaxf(acc[b], 0.f);
    }
    __syncthreads();

    // layer 2: h2[b][o] = relu(w2[o,:] . h1[b,:] + b2[o]) -> bf16
    {
        float acc[4];
        #pragma unroll
        for (int b = 0; b < 4; b++) acc[b] = b2[i];
        for (int k = 0; k < 128; k += 4) {
            float4 w = *(const float4*)&w2[i * 128 + k];
            #pragma unroll
            for (int b = 0; b < 4; b++) {
                float4 h = *(const float4*)&h1_lds[(g + b) * 128 + k];  // ds_read_b128, broadcast
                acc[b] += w.x * h.x + w.y * h.y + w.z * h.z + w.w * h.w;
            }
        }
        #pragma unroll
        for (int b = 0; b < 4; b++)
            h2b[(long)(b0 + g + b) * 128 + i] = f2bf(fmaxf(acc[b], 0.f));
    }
}

// ---------------- Kg: wide-term gather via LDS row staging ----------------
// 2500 blocks x 256 threads; block owns 4 w_head rows.
// Per row: coalesced float4 stage (HBM floor), then 4096 ds_read_b32 gathers,
// pack bf16 pairs -> coalesced u32 stores. Also emits dense bf16 Wd row.
#define KG_ROWS 4
__global__ __launch_bounds__(256) void kg_gather(
    const int* __restrict__ inter,
    const float* __restrict__ w_head,
    unsigned short* __restrict__ wg,
    unsigned short* __restrict__ wd)
{
    __shared__ float row_lds[HEADCOLS];   // 40.5 KB -> 3 blocks/CU
    const int t  = threadIdx.x;
    const int j0 = blockIdx.x * KG_ROWS;

    // this thread's 8 item-index PAIRS (b = 2p, 2p+1 with p = t + 256*i)
    int c0[8], c1[8];
    #pragma unroll
    for (int i = 0; i < 8; i++) {
        int p = t + 256 * i;
        c0[i] = inter[4 * p + 1];
        c1[i] = inter[4 * p + 3];
    }

    for (int r = 0; r < KG_ROWS; r++) {
        const float* row = w_head + (long)(j0 + r) * HEADCOLS;
        // stage: 2532 x 16B = 10128 floats, coalesced, single-use -> nontemporal
        for (int idx = t; idx < HEADCOLS / 4; idx += 256) {
            floatx4 v = __builtin_nontemporal_load((const floatx4*)row + idx);
            *(floatx4*)&row_lds[idx * 4] = v;
        }
        __syncthreads();

        unsigned* wr = (unsigned*)(wg + (long)(j0 + r) * BATCH);
        #pragma unroll
        for (int i = 0; i < 8; i++) {
            unsigned lo = f2bf(row_lds[c0[i]]);
            unsigned hi = f2bf(row_lds[c1[i]]);
            __builtin_nontemporal_store(lo | (hi << 16), &wr[t + 256 * i]);
        }
        // dense cols -> bf16 Wd (reused 32x by k2, keep cached)
        if (t < 128) wd[(long)(j0 + r) * 128 + t] = f2bf(row_lds[DENSEOFF + t]);
        __syncthreads();
    }
}

// ---------------- K2: fused head (Wg + Wd path) ----------------
// Tile 128(b) x 128(j), 4 waves (2x2), 16x16x32 bf16 MFMA, K=128 in one shot.
#define LDSTR 136   // 128 + 8 bf16 pad (16B-aligned rows, 2-way-max bank aliasing)

__global__ __launch_bounds__(256) void k2_head(
    const unsigned short* __restrict__ h2b,
    const unsigned short* __restrict__ wd, const float* __restrict__ b_head,
    const unsigned short* __restrict__ wg, float* __restrict__ out)
{
    __shared__ short A_lds[128 * LDSTR];
    __shared__ short B_lds[128 * LDSTR];

    const int t     = threadIdx.x;
    const int bbase = blockIdx.x * 128;   // b-tiles fast -> adjacent blocks share j-tile (L2/L3 reuse)
    const int jbase = blockIdx.y * 128;

    // stage A: h2 tile (128 x 128 bf16), 16B chunks
    for (int idx = t; idx < 128 * 16; idx += 256) {
        int r = idx >> 4, s = idx & 15;
        short8 v = *(const short8*)&h2b[(long)(bbase + r) * 128 + s * 8];
        *(short8*)&A_lds[r * LDSTR + s * 8] = v;
    }
    // stage B: dense bf16 rows from Wd (pre-converted by kg)
    for (int idx = t; idx < 128 * 16; idx += 256) {
        int r = idx >> 4, s = idx & 15;
        int j = jbase + r;
        short8 v;
        if (j < NITEMS) v = *(const short8*)&wd[(long)j * 128 + s * 8];
        else { v[0]=0;v[1]=0;v[2]=0;v[3]=0;v[4]=0;v[5]=0;v[6]=0;v[7]=0; }
        *(short8*)&B_lds[r * LDSTR + s * 8] = v;
    }
    __syncthreads();

    const int lane = t & 63, wave = t >> 6;
    const int wb = (wave & 1) * 64, wj = (wave >> 1) * 64;
    const int col = lane & 15, quad = lane >> 4;

    floatx4 acc[4][4];
    #pragma unroll
    for (int bi = 0; bi < 4; bi++)
        #pragma unroll
        for (int ji = 0; ji < 4; ji++)
            #pragma unroll
            for (int r = 0; r < 4; r++) acc[bi][ji][r] = 0.f;

    // K = 128 = 4 x 32
    #pragma unroll
    for (int ks = 0; ks < 4; ks++) {
        short8 a[4], b[4];
        #pragma unroll
        for (int bi = 0; bi < 4; bi++)
            a[bi] = *(const short8*)&A_lds[(wb + bi * 16 + col) * LDSTR + ks * 32 + quad * 8];
        #pragma unroll
        for (int ji = 0; ji < 4; ji++)
            b[ji] = *(const short8*)&B_lds[(wj + ji * 16 + col) * LDSTR + ks * 32 + quad * 8];
        #pragma unroll
        for (int bi = 0; bi < 4; bi++)
            #pragma unroll
            for (int ji = 0; ji < 4; ji++)
                acc[bi][ji] = __builtin_amdgcn_mfma_f32_16x16x32_bf16(a[bi], b[ji], acc[bi][ji], 0, 0, 0);
    }

    // epilogue: + bias + wide (coalesced from Wg), sigmoid, store.
    // C/D layout: col = lane&15, row = quad*4 + reg  (m89-verified)
    #pragma unroll
    for (int ji = 0; ji < 4; ji++) {
        int j = jbase + wj + ji * 16 + col;
        bool jv = (j < NITEMS);
        float bias = jv ? b_head[j] : 0.f;
        const unsigned short* wgr = wg + (long)(jv ? j : 0) * BATCH + bbase;
        #pragma unroll
        for (int bi = 0; bi < 4; bi++) {
            short4v wv = *(const short4v*)&wgr[wb + bi * 16 + quad * 4];   // 8B; bi-pairs share 64B lines
            #pragma unroll
            for (int r = 0; r < 4; r++) {
                int bl = wb + bi * 16 + quad * 4 + r;
                float wide = bf2f((unsigned short)wv[r]);
                float x = acc[bi][ji][r] + bias + wide;
                float y = 1.f / (1.f + __expf(-x));
                if (jv) __builtin_nontemporal_store(y, &out[(long)(bbase + bl) * NITEMS + j]);
            }
        }
    }
}

// ---------------- K2 fallback: original scattered-gather head ----------------
// Used only if workspace can't hold Wg+Wd (~85 MB).
__global__ __launch_bounds__(256) void k2_head_fb(
    const unsigned short* __restrict__ h2b,
    const float* __restrict__ w_head, const float* __restrict__ b_head,
    const int* __restrict__ inter, float* __restrict__ out)
{
    __shared__ short A_lds[128 * LDSTR];
    __shared__ short B_lds[128 * LDSTR];
    __shared__ int items[128];

    const int t     = threadIdx.x;
    const int bbase = blockIdx.x * 128;
    const int jbase = blockIdx.y * 128;

    if (t < 128) items[t] = inter[2 * (bbase + t) + 1];

    for (int idx = t; idx < 128 * 16; idx += 256) {
        int r = idx >> 4, s = idx & 15;
        short8 v = *(const short8*)&h2b[(long)(bbase + r) * 128 + s * 8];
        *(short8*)&A_lds[r * LDSTR + s * 8] = v;
    }
    for (int idx = t; idx < 128 * 32; idx += 256) {
        int r = idx >> 5, s = idx & 31;
        int j = jbase + r;
        short4v o4;
        if (j < NITEMS) {
            float4 w = *(const float4*)&w_head[(long)j * HEADCOLS + DENSEOFF + s * 4];
            o4[0] = (short)f2bf(w.x); o4[1] = (short)f2bf(w.y);
            o4[2] = (short)f2bf(w.z); o4[3] = (short)f2bf(w.w);
        } else {
            o4[0] = 0; o4[1] = 0; o4[2] = 0; o4[3] = 0;
        }
        *(short4v*)&B_lds[r * LDSTR + s * 4] = o4;
    }
    __syncthreads();

    const int lane = t & 63, wave = t >> 6;
    const int wb = (wave & 1) * 64, wj = (wave >> 1) * 64;
    const int col = lane & 15, quad = lane >> 4;

    floatx4 acc[4][4];
    #pragma unroll
    for (int bi = 0; bi < 4; bi++)
        #pragma unroll
        for (int ji = 0; ji < 4; ji++)
            #pragma unroll
            for (int r = 0; r < 4; r++) acc[bi][ji][r] = 0.f;

    #pragma unroll
    for (int ks = 0; ks < 4; ks++) {
        short8 a[4], b[4];
        #pragma unroll
        for (int bi = 0; bi < 4; bi++)
            a[bi] = *(const short8*)&A_lds[(wb + bi * 16 + col) * LDSTR + ks * 32 + quad * 8];
        #pragma unroll
        for (int ji = 0; ji < 4; ji++)
            b[ji] = *(const short8*)&B_lds[(wj + ji * 16 + col) * LDSTR + ks * 32 + quad * 8];
        #pragma unroll
        for (int bi = 0; bi < 4; bi++)
            #pragma unroll
            for (int ji = 0; ji < 4; ji++)
                acc[bi][ji] = __builtin_amdgcn_mfma_f32_16x16x32_bf16(a[bi], b[ji], acc[bi][ji], 0, 0, 0);
    }

    #pragma unroll
    for (int ji = 0; ji < 4; ji++) {
        int j = jbase + wj + ji * 16 + col;
        bool jv = (j < NITEMS);
        float bias = jv ? b_head[j] : 0.f;
        const float* wrow = w_head + (long)(jv ? j : 0) * HEADCOLS;
        #pragma unroll
        for (int bi = 0; bi < 4; bi++) {
            #pragma unroll
            for (int r = 0; r < 4; r++) {
                int bl = wb + bi * 16 + quad * 4 + r;
                float wide = jv ? wrow[items[bl]] : 0.f;
                float x = acc[bi][ji][r] + bias + wide;
                float y = 1.f / (1.f + __expf(-x));
                if (jv) out[(long)(bbase + bl) * NITEMS + j] = y;
            }
        }
    }
}

extern "C" void kernel_launch(void* const* d_in, const int* in_sizes, int n_in,
                              void* d_out, int out_size, void* d_ws, size_t ws_size,
                              hipStream_t stream) {
    const int*   inter = (const int*)d_in[0];
    const float* U     = (const float*)d_in[1];
    const float* I     = (const float*)d_in[2];
    const float* w1    = (const float*)d_in[3];
    const float* b1    = (const float*)d_in[4];
    const float* w2    = (const float*)d_in[5];
    const float* b2    = (const float*)d_in[6];
    const float* wh    = (const float*)d_in[7];
    const float* bh    = (const float*)d_in[8];
    float* out = (float*)d_out;

    unsigned short* h2b = (unsigned short*)d_ws;        // 4096*128 bf16 = 1 MB
    const size_t WG_OFF  = 1u << 20;
    const size_t WG_SIZE = (size_t)NITEMS * BATCH * 2;  // ~82 MB bf16
    const size_t WD_OFF  = WG_OFF + WG_SIZE;            // 16B-aligned
    const size_t WD_SIZE = (size_t)NITEMS * 128 * 2;    // 2.56 MB bf16

    k1_mlp<<<512, 256, 0, stream>>>(inter, U, I, w1, b1, w2, b2, h2b);

    if (ws_size >= WD_OFF + WD_SIZE) {
        unsigned short* wg = (unsigned short*)((char*)d_ws + WG_OFF);
        unsigned short* wd = (unsigned short*)((char*)d_ws + WD_OFF);
        kg_gather<<<NITEMS / KG_ROWS, 256, 0, stream>>>(inter, wh, wg, wd);
        k2_head<<<dim3(32, 79), 256, 0, stream>>>(h2b, wd, bh, wg, out);
    } else {
        k2_head_fb<<<dim3(32, 79), 256, 0, stream>>>(h2b, wh, bh, inter, out);
    }
}

// Round 4
// 646.968 us; speedup vs baseline: 1.5688x; 1.0685x over previous
//
#include <hip/hip_runtime.h>

// Wide & Deep forward, MI355X.
// K1g (merged): blocks [0,2500): per w_head row, stage 40.5KB row to LDS with a
//     register-prefetch pipeline (next row's loads in flight during current row's
//     LDS gather), emit Wg[j][b] bf16 (cache-resident for K2) + dense bf16 Wd.
//     blocks [2500,3012): embeddings + 2-layer MLP -> h2 (4096x128) bf16.
// K2: fused head: out = sigmoid(h2 @ Wd^T + Wg + b_head), 128x128 MFMA tiles.

#define BATCH    4096
#define NITEMS   10000
#define HEADCOLS 10128   // 10000 one-hot + 128 dense
#define DENSEOFF 10000
#define KG_ROWS  4
#define KG_BLOCKS (NITEMS / KG_ROWS)   // 2500
#define MLP_BLOCKS 512
#define ROWCHUNKS 10                   // ceil(2532/256) float4 chunks per thread

typedef __attribute__((ext_vector_type(8))) short short8;
typedef __attribute__((ext_vector_type(4))) short short4v;
typedef __attribute__((ext_vector_type(4))) float floatx4;

__device__ inline unsigned short f2bf(float f) {
    unsigned u = __builtin_bit_cast(unsigned, f);
    unsigned r = (u + 0x7FFFu + ((u >> 16) & 1u)) >> 16;
    return (unsigned short)r;
}

__device__ inline float bf2f(unsigned short u) {
    unsigned x = ((unsigned)u) << 16;
    return __builtin_bit_cast(float, x);
}

// ---------------- K1g: gather + MLP in one launch ----------------
__global__ __launch_bounds__(256) void k1g(
    const int* __restrict__ inter,
    const float* __restrict__ U, const float* __restrict__ I,
    const float* __restrict__ w1, const float* __restrict__ b1,
    const float* __restrict__ w2, const float* __restrict__ b2,
    const float* __restrict__ w_head,
    unsigned short* __restrict__ h2b,
    unsigned short* __restrict__ wg,
    unsigned short* __restrict__ wd)
{
    __shared__ float lds[HEADCOLS];   // 40.5 KB (gather row / MLP scratch union) -> 3 blocks/CU
    const int t   = threadIdx.x;
    const int bid = blockIdx.x;

    if (bid < KG_BLOCKS) {
        // ---- wide-term gather, register-pipelined row staging ----
        const int j0 = bid * KG_ROWS;

        // this thread's 8 item-index PAIRS (b = 2p, 2p+1 with p = t + 256*i)
        int c0[8], c1[8];
        #pragma unroll
        for (int i = 0; i < 8; i++) {
            int p = t + 256 * i;
            c0[i] = inter[4 * p + 1];
            c1[i] = inter[4 * p + 3];
        }

        floatx4 buf[ROWCHUNKS];
        // prefetch row 0
        {
            const floatx4* src = (const floatx4*)(w_head + (long)j0 * HEADCOLS);
            #pragma unroll
            for (int i = 0; i < ROWCHUNKS; i++) {
                int idx = t + 256 * i;
                if (idx < HEADCOLS / 4) buf[i] = __builtin_nontemporal_load(src + idx);
            }
        }

        for (int r = 0; r < KG_ROWS; r++) {
            __syncthreads();   // previous row's gathers complete before overwrite
            #pragma unroll
            for (int i = 0; i < ROWCHUNKS; i++) {
                int idx = t + 256 * i;
                if (idx < HEADCOLS / 4) *(floatx4*)&lds[idx * 4] = buf[i];
            }
            __syncthreads();   // row r staged

            // issue row r+1 loads now; they fly during the gather below
            if (r + 1 < KG_ROWS) {
                const floatx4* src = (const floatx4*)(w_head + (long)(j0 + r + 1) * HEADCOLS);
                #pragma unroll
                for (int i = 0; i < ROWCHUNKS; i++) {
                    int idx = t + 256 * i;
                    if (idx < HEADCOLS / 4) buf[i] = __builtin_nontemporal_load(src + idx);
                }
            }

            // gather row r from LDS, pack bf16 pairs, coalesced u32 stores
            // (plain stores: Wg is L3-resident for k2's immediate read)
            unsigned* wr = (unsigned*)(wg + (long)(j0 + r) * BATCH);
            #pragma unroll
            for (int i = 0; i < 8; i++) {
                unsigned lo = f2bf(lds[c0[i]]);
                unsigned hi = f2bf(lds[c1[i]]);
                wr[t + 256 * i] = lo | (hi << 16);
            }
            // dense cols -> bf16 Wd (reused 32x by k2)
            if (t < 128) wd[(long)(j0 + r) * 128 + t] = f2bf(lds[DENSEOFF + t]);
        }
    } else {
        // ---- MLP path: 8 batch rows per block ----
        float* e_lds  = lds;        // 8 x 64
        float* h1_lds = lds + 512;  // 8 x 128
        const int b0 = (bid - KG_BLOCKS) * 8;

        for (int idx = t; idx < 8 * 64; idx += 256) {
            int b = idx >> 6, d = idx & 63;
            int u  = inter[2 * (b0 + b)];
            int it = inter[2 * (b0 + b) + 1];
            e_lds[idx] = (d < 32) ? U[(long)u * 32 + d] : I[(long)it * 32 + (d - 32)];
        }
        __syncthreads();

        const int i = t & 127;
        const int g = (t >> 7) * 4;   // 2 groups x 4 rows

        // layer 1
        {
            float acc[4];
            #pragma unroll
            for (int b = 0; b < 4; b++) acc[b] = b1[i];
            for (int d = 0; d < 64; d += 4) {
                float4 w = *(const float4*)&w1[i * 64 + d];
                #pragma unroll
                for (int b = 0; b < 4; b++) {
                    float4 e = *(const float4*)&e_lds[(g + b) * 64 + d];  // ds_read_b128
                    acc[b] += w.x * e.x + w.y * e.y + w.z * e.z + w.w * e.w;
                }
            }
            #pragma unroll
            for (int b = 0; b < 4; b++) h1_lds[(g + b) * 128 + i] = fmaxf(acc[b], 0.f);
        }
        __syncthreads();

        // layer 2 -> bf16
        {
            float acc[4];
            #pragma unroll
            for (int b = 0; b < 4; b++) acc[b] = b2[i];
            for (int k = 0; k < 128; k += 4) {
                float4 w = *(const float4*)&w2[i * 128 + k];
                #pragma unroll
                for (int b = 0; b < 4; b++) {
                    float4 h = *(const float4*)&h1_lds[(g + b) * 128 + k];  // ds_read_b128
                    acc[b] += w.x * h.x + w.y * h.y + w.z * h.z + w.w * h.w;
                }
            }
            #pragma unroll
            for (int b = 0; b < 4; b++)
                h2b[(long)(b0 + g + b) * 128 + i] = f2bf(fmaxf(acc[b], 0.f));
        }
    }
}

// ---------------- K1 standalone (fallback path only) ----------------
__global__ __launch_bounds__(256) void k1_mlp(
    const int* __restrict__ inter,
    const float* __restrict__ U, const float* __restrict__ I,
    const float* __restrict__ w1, const float* __restrict__ b1,
    const float* __restrict__ w2, const float* __restrict__ b2,
    unsigned short* __restrict__ h2b)
{
    __shared__ float e_lds[8 * 64];
    __shared__ float h1_lds[8 * 128];
    const int t  = threadIdx.x;
    const int b0 = blockIdx.x * 8;

    for (int idx = t; idx < 8 * 64; idx += 256) {
        int b = idx >> 6, d = idx & 63;
        int u  = inter[2 * (b0 + b)];
        int it = inter[2 * (b0 + b) + 1];
        e_lds[idx] = (d < 32) ? U[(long)u * 32 + d] : I[(long)it * 32 + (d - 32)];
    }
    __syncthreads();

    const int i = t & 127;
    const int g = (t >> 7) * 4;

    {
        float acc[4];
        #pragma unroll
        for (int b = 0; b < 4; b++) acc[b] = b1[i];
        for (int d = 0; d < 64; d += 4) {
            float4 w = *(const float4*)&w1[i * 64 + d];
            #pragma unroll
            for (int b = 0; b < 4; b++) {
                float4 e = *(const float4*)&e_lds[(g + b) * 64 + d];
                acc[b] += w.x * e.x + w.y * e.y + w.z * e.z + w.w * e.w;
            }
        }
        #pragma unroll
        for (int b = 0; b < 4; b++) h1_lds[(g + b) * 128 + i] = fmaxf(acc[b], 0.f);
    }
    __syncthreads();

    {
        float acc[4];
        #pragma unroll
        for (int b = 0; b < 4; b++) acc[b] = b2[i];
        for (int k = 0; k < 128; k += 4) {
            float4 w = *(const float4*)&w2[i * 128 + k];
            #pragma unroll
            for (int b = 0; b < 4; b++) {
                float4 h = *(const float4*)&h1_lds[(g + b) * 128 + k];
                acc[b] += w.x * h.x + w.y * h.y + w.z * h.z + w.w * h.w;
            }
        }
        #pragma unroll
        for (int b = 0; b < 4; b++)
            h2b[(long)(b0 + g + b) * 128 + i] = f2bf(fmaxf(acc[b], 0.f));
    }
}

// ---------------- K2: fused head (Wg + Wd path) ----------------
// Tile 128(b) x 128(j), 4 waves (2x2), 16x16x32 bf16 MFMA, K=128 in one shot.
#define LDSTR 136   // 128 + 8 bf16 pad (16B-aligned rows, 2-way-max bank aliasing)

__global__ __launch_bounds__(256) void k2_head(
    const unsigned short* __restrict__ h2b,
    const unsigned short* __restrict__ wd, const float* __restrict__ b_head,
    const unsigned short* __restrict__ wg, float* __restrict__ out)
{
    __shared__ short A_lds[128 * LDSTR];
    __shared__ short B_lds[128 * LDSTR];

    const int t     = threadIdx.x;
    const int bbase = blockIdx.x * 128;   // b-tiles fast -> adjacent blocks share j-tile (L2/L3 reuse)
    const int jbase = blockIdx.y * 128;

    // stage A: h2 tile (128 x 128 bf16), 16B chunks
    for (int idx = t; idx < 128 * 16; idx += 256) {
        int r = idx >> 4, s = idx & 15;
        short8 v = *(const short8*)&h2b[(long)(bbase + r) * 128 + s * 8];
        *(short8*)&A_lds[r * LDSTR + s * 8] = v;
    }
    // stage B: dense bf16 rows from Wd (pre-converted by k1g)
    for (int idx = t; idx < 128 * 16; idx += 256) {
        int r = idx >> 4, s = idx & 15;
        int j = jbase + r;
        short8 v;
        if (j < NITEMS) v = *(const short8*)&wd[(long)j * 128 + s * 8];
        else { v[0]=0;v[1]=0;v[2]=0;v[3]=0;v[4]=0;v[5]=0;v[6]=0;v[7]=0; }
        *(short8*)&B_lds[r * LDSTR + s * 8] = v;
    }
    __syncthreads();

    const int lane = t & 63, wave = t >> 6;
    const int wb = (wave & 1) * 64, wj = (wave >> 1) * 64;
    const int col = lane & 15, quad = lane >> 4;

    floatx4 acc[4][4];
    #pragma unroll
    for (int bi = 0; bi < 4; bi++)
        #pragma unroll
        for (int ji = 0; ji < 4; ji++)
            #pragma unroll
            for (int r = 0; r < 4; r++) acc[bi][ji][r] = 0.f;

    // K = 128 = 4 x 32
    #pragma unroll
    for (int ks = 0; ks < 4; ks++) {
        short8 a[4], b[4];
        #pragma unroll
        for (int bi = 0; bi < 4; bi++)
            a[bi] = *(const short8*)&A_lds[(wb + bi * 16 + col) * LDSTR + ks * 32 + quad * 8];
        #pragma unroll
        for (int ji = 0; ji < 4; ji++)
            b[ji] = *(const short8*)&B_lds[(wj + ji * 16 + col) * LDSTR + ks * 32 + quad * 8];
        #pragma unroll
        for (int bi = 0; bi < 4; bi++)
            #pragma unroll
            for (int ji = 0; ji < 4; ji++)
                acc[bi][ji] = __builtin_amdgcn_mfma_f32_16x16x32_bf16(a[bi], b[ji], acc[bi][ji], 0, 0, 0);
    }

    // epilogue: + bias + wide (coalesced from Wg, L3-hot), sigmoid, store.
    // C/D layout: col = lane&15, row = quad*4 + reg  (m89-verified)
    #pragma unroll
    for (int ji = 0; ji < 4; ji++) {
        int j = jbase + wj + ji * 16 + col;
        bool jv = (j < NITEMS);
        float bias = jv ? b_head[j] : 0.f;
        const unsigned short* wgr = wg + (long)(jv ? j : 0) * BATCH + bbase;
        #pragma unroll
        for (int bi = 0; bi < 4; bi++) {
            short4v wv = *(const short4v*)&wgr[wb + bi * 16 + quad * 4];   // 8B; bi-pairs share 64B lines
            #pragma unroll
            for (int r = 0; r < 4; r++) {
                int bl = wb + bi * 16 + quad * 4 + r;
                float wide = bf2f((unsigned short)wv[r]);
                float x = acc[bi][ji][r] + bias + wide;
                float y = 1.f / (1.f + __expf(-x));
                if (jv) __builtin_nontemporal_store(y, &out[(long)(bbase + bl) * NITEMS + j]);
            }
        }
    }
}

// ---------------- K2 fallback: original scattered-gather head ----------------
// Used only if workspace can't hold Wg+Wd (~85 MB).
__global__ __launch_bounds__(256) void k2_head_fb(
    const unsigned short* __restrict__ h2b,
    const float* __restrict__ w_head, const float* __restrict__ b_head,
    const int* __restrict__ inter, float* __restrict__ out)
{
    __shared__ short A_lds[128 * LDSTR];
    __shared__ short B_lds[128 * LDSTR];
    __shared__ int items[128];

    const int t     = threadIdx.x;
    const int bbase = blockIdx.x * 128;
    const int jbase = blockIdx.y * 128;

    if (t < 128) items[t] = inter[2 * (bbase + t) + 1];

    for (int idx = t; idx < 128 * 16; idx += 256) {
        int r = idx >> 4, s = idx & 15;
        short8 v = *(const short8*)&h2b[(long)(bbase + r) * 128 + s * 8];
        *(short8*)&A_lds[r * LDSTR + s * 8] = v;
    }
    for (int idx = t; idx < 128 * 32; idx += 256) {
        int r = idx >> 5, s = idx & 31;
        int j = jbase + r;
        short4v o4;
        if (j < NITEMS) {
            float4 w = *(const float4*)&w_head[(long)j * HEADCOLS + DENSEOFF + s * 4];
            o4[0] = (short)f2bf(w.x); o4[1] = (short)f2bf(w.y);
            o4[2] = (short)f2bf(w.z); o4[3] = (short)f2bf(w.w);
        } else {
            o4[0] = 0; o4[1] = 0; o4[2] = 0; o4[3] = 0;
        }
        *(short4v*)&B_lds[r * LDSTR + s * 4] = o4;
    }
    __syncthreads();

    const int lane = t & 63, wave = t >> 6;
    const int wb = (wave & 1) * 64, wj = (wave >> 1) * 64;
    const int col = lane & 15, quad = lane >> 4;

    floatx4 acc[4][4];
    #pragma unroll
    for (int bi = 0; bi < 4; bi++)
        #pragma unroll
        for (int ji = 0; ji < 4; ji++)
            #pragma unroll
            for (int r = 0; r < 4; r++) acc[bi][ji][r] = 0.f;

    #pragma unroll
    for (int ks = 0; ks < 4; ks++) {
        short8 a[4], b[4];
        #pragma unroll
        for (int bi = 0; bi < 4; bi++)
            a[bi] = *(const short8*)&A_lds[(wb + bi * 16 + col) * LDSTR + ks * 32 + quad * 8];
        #pragma unroll
        for (int ji = 0; ji < 4; ji++)
            b[ji] = *(const short8*)&B_lds[(wj + ji * 16 + col) * LDSTR + ks * 32 + quad * 8];
        #pragma unroll
        for (int bi = 0; bi < 4; bi++)
            #pragma unroll
            for (int ji = 0; ji < 4; ji++)
                acc[bi][ji] = __builtin_amdgcn_mfma_f32_16x16x32_bf16(a[bi], b[ji], acc[bi][ji], 0, 0, 0);
    }

    #pragma unroll
    for (int ji = 0; ji < 4; ji++) {
        int j = jbase + wj + ji * 16 + col;
        bool jv = (j < NITEMS);
        float bias = jv ? b_head[j] : 0.f;
        const float* wrow = w_head + (long)(jv ? j : 0) * HEADCOLS;
        #pragma unroll
        for (int bi = 0; bi < 4; bi++) {
            #pragma unroll
            for (int r = 0; r < 4; r++) {
                int bl = wb + bi * 16 + quad * 4 + r;
                float wide = jv ? wrow[items[bl]] : 0.f;
                float x = acc[bi][ji][r] + bias + wide;
                float y = 1.f / (1.f + __expf(-x));
                if (jv) out[(long)(bbase + bl) * NITEMS + j] = y;
            }
        }
    }
}

extern "C" void kernel_launch(void* const* d_in, const int* in_sizes, int n_in,
                              void* d_out, int out_size, void* d_ws, size_t ws_size,
                              hipStream_t stream) {
    const int*   inter = (const int*)d_in[0];
    const float* U     = (const float*)d_in[1];
    const float* I     = (const float*)d_in[2];
    const float* w1    = (const float*)d_in[3];
    const float* b1    = (const float*)d_in[4];
    const float* w2    = (const float*)d_in[5];
    const float* b2    = (const float*)d_in[6];
    const float* wh    = (const float*)d_in[7];
    const float* bh    = (const float*)d_in[8];
    float* out = (float*)d_out;

    unsigned short* h2b = (unsigned short*)d_ws;        // 4096*128 bf16 = 1 MB
    const size_t WG_OFF  = 1u << 20;
    const size_t WG_SIZE = (size_t)NITEMS * BATCH * 2;  // ~82 MB bf16
    const size_t WD_OFF  = WG_OFF + WG_SIZE;            // 16B-aligned
    const size_t WD_SIZE = (size_t)NITEMS * 128 * 2;    // 2.56 MB bf16

    if (ws_size >= WD_OFF + WD_SIZE) {
        unsigned short* wg = (unsigned short*)((char*)d_ws + WG_OFF);
        unsigned short* wd = (unsigned short*)((char*)d_ws + WD_OFF);
        k1g<<<KG_BLOCKS + MLP_BLOCKS, 256, 0, stream>>>(inter, U, I, w1, b1, w2, b2, wh, h2b, wg, wd);
        k2_head<<<dim3(32, 79), 256, 0, stream>>>(h2b, wd, bh, wg, out);
    } else {
        k1_mlp<<<512, 256, 0, stream>>>(inter, U, I, w1, b1, w2, b2, h2b);
        k2_head_fb<<<dim3(32, 79), 256, 0, stream>>>(h2b, wh, bh, inter, out);
    }
}